// Round 1
// baseline (17295.303 us; speedup 1.0000x reference)
//
#include <hip/hip_runtime.h>
#include <math.h>

#define BATCH 64
#define SEQ 512
#define DIM 1024
#define HID 1024
#define KBANDS 4
#define DT_C 0.05f

// ---------------- alpha: softmax tau mixer -> alpha[b] ----------------
__global__ void alpha_kernel(const float* __restrict__ complexity,
                             const float* __restrict__ tau_bands,
                             const float* __restrict__ mixer_w,
                             const float* __restrict__ mixer_b,
                             float* __restrict__ alpha) {
    int b = threadIdx.x;
    if (b < BATCH) {
        float c = complexity[b];
        float lg[KBANDS];
        float mx = -1e30f;
        #pragma unroll
        for (int k = 0; k < KBANDS; k++) {
            lg[k] = c * mixer_w[k] + mixer_b[k];
            mx = fmaxf(mx, lg[k]);
        }
        float se = 0.f, tau = 0.f;
        #pragma unroll
        for (int k = 0; k < KBANDS; k++) {
            float e = expf(lg[k] - mx);
            se += e;
            tau += tau_bands[k] * e;
        }
        tau /= se;
        alpha[b] = expf(-DT_C / tau);
    }
}

// ------------- transpose + pack W_rec:  WT4[(k>>2)*4096 + j*4 + (k&3)] = Wrec[j*H+k]
__global__ void transpose_kernel(const float* __restrict__ Wrec, float* __restrict__ WT4) {
    __shared__ float tile[32][33];
    int bk = blockIdx.x * 32;  // k base
    int bj = blockIdx.y * 32;  // j base
    int tx = threadIdx.x, ty = threadIdx.y;  // 32 x 8
    #pragma unroll
    for (int i = 0; i < 32; i += 8)
        tile[ty + i][tx] = Wrec[(size_t)(bj + ty + i) * HID + bk + tx];
    __syncthreads();
    #pragma unroll
    for (int i = 0; i < 32; i += 8) {
        int kk = ty + i;              // k offset within block
        int k = bk + kk;
        int j = bj + tx;
        WT4[(size_t)(k >> 2) * (HID * 4) + (size_t)j * 4 + (k & 3)] = tile[tx][kk];
    }
}

// ------------- xw = x @ W_in^T + bias, written into d_out's output region -------------
// C[m,n] = sum_k x[m,k] * Win[n*1024 + k] + bias[n];  M=32768, N=1024, K=1024
#define BM 64
#define BN 64
#define BK 16
__global__ __launch_bounds__(256) void in_gemm(const float* __restrict__ x,
                                               const float* __restrict__ Win,
                                               const float* __restrict__ bias,
                                               float* __restrict__ out) {
    __shared__ float As[BK][BM + 4];
    __shared__ float Bs[BK][BN + 4];
    int tid = threadIdx.x;
    int tx = tid & 15, ty = tid >> 4;
    int m0 = blockIdx.x * BM;
    int n0 = blockIdx.y * BN;
    float c[4][4] = {};
    int lmm = tid >> 2;            // 0..63
    int lkq = (tid & 3) * 4;       // 0,4,8,12
    for (int k0 = 0; k0 < 1024; k0 += BK) {
        float4 a4 = *(const float4*)(x + (size_t)(m0 + lmm) * 1024 + k0 + lkq);
        float4 b4 = *(const float4*)(Win + (size_t)(n0 + lmm) * 1024 + k0 + lkq);
        As[lkq + 0][lmm] = a4.x; As[lkq + 1][lmm] = a4.y;
        As[lkq + 2][lmm] = a4.z; As[lkq + 3][lmm] = a4.w;
        Bs[lkq + 0][lmm] = b4.x; Bs[lkq + 1][lmm] = b4.y;
        Bs[lkq + 2][lmm] = b4.z; Bs[lkq + 3][lmm] = b4.w;
        __syncthreads();
        #pragma unroll
        for (int kk = 0; kk < BK; kk++) {
            float a[4], bb[4];
            #pragma unroll
            for (int i = 0; i < 4; i++) a[i] = As[kk][ty * 4 + i];
            #pragma unroll
            for (int j = 0; j < 4; j++) bb[j] = Bs[kk][tx * 4 + j];
            #pragma unroll
            for (int i = 0; i < 4; i++)
                #pragma unroll
                for (int j = 0; j < 4; j++)
                    c[i][j] += a[i] * bb[j];
        }
        __syncthreads();
    }
    int n = n0 + tx * 4;
    float4 bias4 = *(const float4*)(bias + n);
    #pragma unroll
    for (int i = 0; i < 4; i++) {
        int m = m0 + ty * 4 + i;
        float4 st;
        st.x = c[i][0] + bias4.x;
        st.y = c[i][1] + bias4.y;
        st.z = c[i][2] + bias4.z;
        st.w = c[i][3] + bias4.w;
        *(float4*)(out + (size_t)m * 1024 + n) = st;
    }
}

// ------------- recurrence: one block per batch element, 1024 threads (one per j) ----
__global__ __launch_bounds__(1024) void recur(const float* __restrict__ WT4,
                                              const float* __restrict__ alpha,
                                              float* __restrict__ out) {
    __shared__ float h[HID];
    int b = blockIdx.x;
    int j = threadIdx.x;
    float a = alpha[b];
    float om = 1.f - a;
    h[j] = 0.f;
    __syncthreads();
    float* outb = out + (size_t)b * SEQ * HID;
    const float* wj = WT4 + (size_t)j * 4;   // column j, packed groups of 4 k's
    float hn = 0.f;
    for (int t = 0; t < SEQ; t++) {
        float acc = outb[(size_t)t * HID + j];  // xw + bias (pre-activation input part)
        #pragma unroll 4
        for (int kg = 0; kg < HID / 4; kg++) {
            float4 w4 = *(const float4*)(wj + (size_t)kg * (HID * 4));
            float4 h4 = *(const float4*)(h + kg * 4);
            acc += h4.x * w4.x + h4.y * w4.y + h4.z * w4.z + h4.w * w4.w;
        }
        float hj = h[j];
        hn = a * hj + om * tanhf(acc);
        __syncthreads();          // all reads of h done
        h[j] = hn;
        outb[(size_t)t * HID + j] = hn;
        __syncthreads();          // writes visible before next step's reads
    }
    out[(size_t)BATCH * SEQ * HID + (size_t)b * HID + j] = hn;
}

extern "C" void kernel_launch(void* const* d_in, const int* in_sizes, int n_in,
                              void* d_out, int out_size, void* d_ws, size_t ws_size,
                              hipStream_t stream) {
    const float* x          = (const float*)d_in[0];
    const float* complexity = (const float*)d_in[1];
    const float* Wrec       = (const float*)d_in[2];
    const float* Win        = (const float*)d_in[3];
    const float* bias       = (const float*)d_in[4];
    const float* tau_bands  = (const float*)d_in[5];
    const float* mixer_w    = (const float*)d_in[6];
    const float* mixer_b    = (const float*)d_in[7];
    float* out = (float*)d_out;

    float* WT4   = (float*)d_ws;                  // 1024*1024 floats = 4 MB
    float* alpha = WT4 + (size_t)HID * HID;       // 64 floats

    alpha_kernel<<<1, 64, 0, stream>>>(complexity, tau_bands, mixer_w, mixer_b, alpha);
    transpose_kernel<<<dim3(32, 32), dim3(32, 8), 0, stream>>>(Wrec, WT4);
    in_gemm<<<dim3(32768 / BM, 1024 / BN), 256, 0, stream>>>(x, Win, bias, out);
    recur<<<BATCH, 1024, 0, stream>>>(WT4, alpha, out);
}

// Round 2
// 12233.888 us; speedup vs baseline: 1.4137x; 1.4137x over previous
//
#include <hip/hip_runtime.h>
#include <math.h>

#define BATCH 64
#define SEQ 512
#define DIM 1024
#define HID 1024
#define KBANDS 4
#define DT_C 0.05f

// ---------------- alpha: softmax tau mixer -> alpha[b] ----------------
__global__ void alpha_kernel(const float* __restrict__ complexity,
                             const float* __restrict__ tau_bands,
                             const float* __restrict__ mixer_w,
                             const float* __restrict__ mixer_b,
                             float* __restrict__ alpha) {
    int b = threadIdx.x;
    if (b < BATCH) {
        float c = complexity[b];
        float lg[KBANDS];
        float mx = -1e30f;
        #pragma unroll
        for (int k = 0; k < KBANDS; k++) {
            lg[k] = c * mixer_w[k] + mixer_b[k];
            mx = fmaxf(mx, lg[k]);
        }
        float se = 0.f, tau = 0.f;
        #pragma unroll
        for (int k = 0; k < KBANDS; k++) {
            float e = expf(lg[k] - mx);
            se += e;
            tau += tau_bands[k] * e;
        }
        tau /= se;
        alpha[b] = expf(-DT_C / tau);
    }
}

// ------------- xw = x @ W_in^T + bias, written into d_out's output region -------------
#define BM 64
#define BN 64
#define BK 16
__global__ __launch_bounds__(256) void in_gemm(const float* __restrict__ x,
                                               const float* __restrict__ Win,
                                               const float* __restrict__ bias,
                                               float* __restrict__ out) {
    __shared__ float As[BK][BM + 4];
    __shared__ float Bs[BK][BN + 4];
    int tid = threadIdx.x;
    int tx = tid & 15, ty = tid >> 4;
    int m0 = blockIdx.x * BM;
    int n0 = blockIdx.y * BN;
    float c[4][4] = {};
    int lmm = tid >> 2;
    int lkq = (tid & 3) * 4;
    for (int k0 = 0; k0 < 1024; k0 += BK) {
        float4 a4 = *(const float4*)(x + (size_t)(m0 + lmm) * 1024 + k0 + lkq);
        float4 b4 = *(const float4*)(Win + (size_t)(n0 + lmm) * 1024 + k0 + lkq);
        As[lkq + 0][lmm] = a4.x; As[lkq + 1][lmm] = a4.y;
        As[lkq + 2][lmm] = a4.z; As[lkq + 3][lmm] = a4.w;
        Bs[lkq + 0][lmm] = b4.x; Bs[lkq + 1][lmm] = b4.y;
        Bs[lkq + 2][lmm] = b4.z; Bs[lkq + 3][lmm] = b4.w;
        __syncthreads();
        #pragma unroll
        for (int kk = 0; kk < BK; kk++) {
            float a[4], bb[4];
            #pragma unroll
            for (int i = 0; i < 4; i++) a[i] = As[kk][ty * 4 + i];
            #pragma unroll
            for (int j = 0; j < 4; j++) bb[j] = Bs[kk][tx * 4 + j];
            #pragma unroll
            for (int i = 0; i < 4; i++)
                #pragma unroll
                for (int j = 0; j < 4; j++)
                    c[i][j] += a[i] * bb[j];
        }
        __syncthreads();
    }
    int n = n0 + tx * 4;
    float4 bias4 = *(const float4*)(bias + n);
    #pragma unroll
    for (int i = 0; i < 4; i++) {
        int m = m0 + ty * 4 + i;
        float4 st;
        st.x = c[i][0] + bias4.x;
        st.y = c[i][1] + bias4.y;
        st.z = c[i][2] + bias4.z;
        st.w = c[i][3] + bias4.w;
        *(float4*)(out + (size_t)m * 1024 + n) = st;
    }
}

// ------------- cooperative recurrence --------------------------------------
// 256 blocks = 4 b-slices x 64 j-slices. Block tile per step: 16b x 16j x 1024k.
// W_rec slice (16 rows x 4KB) LDS-resident for the whole sequence.
// h[t] lives in `out` itself (out[b][t][j]); per-(t,bs) atomic counters order
// producers (write out[:,t,:]) against consumers (read it at step t+1).
#define PITCH 1028   // floats per LDS row (1024 + pad, mult of 4 for b128)
#define RPITCH 260

__global__ __launch_bounds__(256) void recur_coop(const float* __restrict__ Wrec,
                                                  const float* __restrict__ alpha,
                                                  float* __restrict__ out,
                                                  int* __restrict__ cnt) {
    extern __shared__ float lds[];
    float* wsl = lds;                 // [16][PITCH] W_rec rows js*16..+15
    float* hs  = lds + 16 * PITCH;    // [16][PITCH] h[t-1] for b-slice
    float* red = lds + 32 * PITCH;    // [16][RPITCH] k-split partials

    int tid = threadIdx.x;
    int bs = blockIdx.x & 3;          // b-slice 0..3
    int js = blockIdx.x >> 2;         // j-slice 0..63
    int ks = tid >> 4;                // 0..15 k-split
    int tb = (tid >> 2) & 3;          // 0..3 (4 b rows)
    int tj = tid & 3;                 // 0..3 (4 j rows)
    int bb = tid >> 4;                // 0..15 (staging / reduce row)
    int l16 = tid & 15;

    // stage W slice once
    {
        const float* src = Wrec + (size_t)(js * 16 + bb) * HID;
        float* dst = wsl + bb * PITCH;
        #pragma unroll
        for (int c = 0; c < 16; c++) {
            int j4 = l16 * 4 + c * 64;
            *(float4*)&dst[j4] = *(const float4*)&src[j4];
        }
    }
    float a_reg = alpha[bs * 16 + bb];
    float om = 1.f - a_reg;
    __syncthreads();

    int jglob = js * 16 + l16;
    int bglob = bs * 16 + bb;
    float* outb = out + (size_t)bglob * SEQ * HID;

    for (int t = 0; t < SEQ; t++) {
        float sum = 0.f, hp = 0.f;
        if (t > 0) {
            if (tid == 0) {
                while (__hip_atomic_fetch_add(&cnt[(t - 1) * 4 + bs], 0,
                        __ATOMIC_ACQUIRE, __HIP_MEMORY_SCOPE_AGENT) < 64)
                    __builtin_amdgcn_s_sleep(2);
            }
            __syncthreads();
            // stage h[t-1] for our 16 batches
            {
                const float* src = outb + ((size_t)(t - 1)) * HID;
                // note: rows of different bb come from different batches:
                const float* srcb = out + ((size_t)bglob * SEQ + (t - 1)) * HID;
                (void)src;
                float* dst = hs + bb * PITCH;
                #pragma unroll
                for (int c = 0; c < 16; c++) {
                    int j4 = l16 * 4 + c * 64;
                    *(float4*)&dst[j4] = *(const float4*)&srcb[j4];
                }
            }
            __syncthreads();
            float cacc[4][4] = {};
            #pragma unroll 4
            for (int m = 0; m < 16; m++) {
                int k = ks * 4 + m * 64;
                float4 av[4], bv[4];
                #pragma unroll
                for (int i = 0; i < 4; i++)
                    av[i] = *(const float4*)&hs[(tb * 4 + i) * PITCH + k];
                #pragma unroll
                for (int i = 0; i < 4; i++)
                    bv[i] = *(const float4*)&wsl[(tj * 4 + i) * PITCH + k];
                #pragma unroll
                for (int i = 0; i < 4; i++)
                    #pragma unroll
                    for (int j = 0; j < 4; j++)
                        cacc[i][j] += av[i].x * bv[j].x + av[i].y * bv[j].y
                                    + av[i].z * bv[j].z + av[i].w * bv[j].w;
            }
            #pragma unroll
            for (int i = 0; i < 4; i++) {
                float4 st; st.x = cacc[i][0]; st.y = cacc[i][1];
                st.z = cacc[i][2]; st.w = cacc[i][3];
                *(float4*)&red[ks * RPITCH + (tb * 4 + i) * 16 + tj * 4] = st;
            }
            __syncthreads();
            #pragma unroll 4
            for (int k2 = 0; k2 < 16; k2++) sum += red[k2 * RPITCH + tid];
            hp = hs[bb * PITCH + jglob];
        }
        float pre = sum + outb[(size_t)t * HID + jglob];
        float hn = a_reg * hp + om * tanhf(pre);
        outb[(size_t)t * HID + jglob] = hn;
        if (t == SEQ - 1)
            out[(size_t)BATCH * SEQ * HID + (size_t)bglob * HID + jglob] = hn;
        __syncthreads();   // all tile writes issued (barrier drains vmcnt)
        if (tid == 0) {
            __threadfence();
            __hip_atomic_fetch_add(&cnt[t * 4 + bs], 1,
                    __ATOMIC_RELEASE, __HIP_MEMORY_SCOPE_AGENT);
        }
    }
}

extern "C" void kernel_launch(void* const* d_in, const int* in_sizes, int n_in,
                              void* d_out, int out_size, void* d_ws, size_t ws_size,
                              hipStream_t stream) {
    const float* x          = (const float*)d_in[0];
    const float* complexity = (const float*)d_in[1];
    const float* Wrec       = (const float*)d_in[2];
    const float* Win        = (const float*)d_in[3];
    const float* bias       = (const float*)d_in[4];
    const float* tau_bands  = (const float*)d_in[5];
    const float* mixer_w    = (const float*)d_in[6];
    const float* mixer_b    = (const float*)d_in[7];
    float* out = (float*)d_out;

    float* alpha = (float*)d_ws;                 // 64 floats
    int*   cnt   = (int*)d_ws + 64;              // 512*4 ints

    hipMemsetAsync(cnt, 0, SEQ * 4 * sizeof(int), stream);
    alpha_kernel<<<1, 64, 0, stream>>>(complexity, tau_bands, mixer_w, mixer_b, alpha);
    in_gemm<<<dim3(32768 / BM, 1024 / BN), 256, 0, stream>>>(x, Win, bias, out);

    const int ldsBytes = (32 * PITCH + 16 * RPITCH) * (int)sizeof(float);  // 148224
    hipFuncSetAttribute((const void*)recur_coop,
                        hipFuncAttributeMaxDynamicSharedMemorySize, ldsBytes);
    void* args[] = { (void*)&Wrec, (void*)&alpha, (void*)&out, (void*)&cnt };
    hipLaunchCooperativeKernel((void*)recur_coop, dim3(256), dim3(256),
                               args, ldsBytes, stream);
}